// Round 9
// baseline (245.314 us; speedup 1.0000x reference)
//
#include <hip/hip_runtime.h>

// (32, 3, 384, 640) fp32 in, (32, 1, 384, 640) fp32 out.
// v9 (resubmit; round-8 run died to a container-level infra failure).
// Channel-split for TLP. v8 post-mortem: zero-spill LDS-free kernel ==
// LDS-pipeline kernel == ~85us, both at ~4 waves/SIMD, VALUBusy ~38%, waves
// ~90% latency-stalled. VALU demand says ~35-40us if hidden. The cap is
// VGPR=84 -> 16 waves/CU. Fix: split the channel loop across threadIdx.z:
//   - block (32,4,3) = 384 thr (6 waves, channel-pure waves); each thread
//     computes ONE channel x ONE output row x 4 px (~1/6 of v8's work).
//   - partial (wssim*ns + wl1*dab per px) combined via 4KB LDS: tz=1,2
//     write, one barrier, tz=0 sums + stores; tz>0 waves exit early.
//   - #pragma unroll 1 row loop: one row's loads in flight at a time ->
//     live set ~55 regs; __launch_bounds__(384,4) caps VGPR at 64
//     (empirical cap=256/arg ladder from v1/v3/v5/v6/v8).
//   - <=64 VGPR -> 32 waves/CU / 6 per block -> 5 blocks/CU = 30 waves
//     resident (7.5/SIMD), ~2-3x v8's residency, no sustained barriers.
//   - reflection as verified in v8: reflected cols live inside the lane's
//     own float4 (reflect(-1)=1 -> .y, reflect(640)=638 -> .z) -> selects;
//     reflected rows via index math; edge scalar addrs clamped in-bounds.
#define BATCH 32
#define CHAN  3
#define HH    384
#define WW    640
#define HW    (HH * WW)
#define NBX   (WW / 128)     // 5
#define TR    4              // output rows per block
#define NBY   (HH / TR)      // 96

__global__ __launch_bounds__(384, 4)
void ssim_l1_kernel(const float* __restrict__ src,
                    const float* __restrict__ tgt,
                    float* __restrict__ out) {
    __shared__ float red[2][TR][32][4];   // tz=1,2 partials: 4096 B

    const int tx = threadIdx.x;           // 0..31
    const int ty = threadIdx.y;           // 0..3
    const int tz = threadIdx.z;           // 0..2  (channel)
    const int bx = blockIdx.x, by = blockIdx.y, b = blockIdx.z;

    const int c0 = bx * 128 + 4 * tx;     // first output col (16B aligned)
    const int oh = by * TR + ty;          // this thread's output row

    // 3 input rows with height reflection at the global edges.
    const int r0 = (oh == 0) ? 1 : oh - 1;            // reflect(-1)=1
    const int r2 = (oh + 1 >= HH) ? HH - 2 : oh + 1;  // reflect(384)=382

    const bool eL = (bx == 0) && (tx == 0);
    const bool eR = (bx == NBX - 1) && (tx == 31);
    const int dl = eL ? 0 : -1;           // in-bounds dummy for edge lanes
    const int dr = eR ? 0 : 4;            // (value replaced by the select)

    const int i0 = r0 * WW + c0;
    const int i1 = oh * WW + c0;
    const int i2 = r2 * WW + c0;

    const float* __restrict__ px = src + ((size_t)b * CHAN + tz) * HW;
    const float* __restrict__ py = tgt + ((size_t)b * CHAN + tz) * HW;

    const float inv9  = 1.0f / 9.0f;
    const float C1v   = 6.5025f;          // (0.01*255)^2
    const float C2v   = 58.5225f;         // (0.03*255)^2
    const float wssim = 0.5f * 0.85f / 3.0f;
    const float wl1   = 0.15f / 3.0f;

    float ax[4], ay[4], as_[4], ap[4], dab[4];
#pragma unroll
    for (int i = 0; i < 4; i++) { ax[i] = 0.f; ay[i] = 0.f; as_[i] = 0.f; ap[i] = 0.f; }

    // Row loop NOT unrolled: keeps only one row's loads in flight (live set
    // ~55 regs); latency hidden by 30-wave/CU TLP, not per-wave hoisting.
#pragma unroll 1
    for (int rr = 0; rr < 3; rr++) {
        const int ib = (rr == 0) ? i0 : (rr == 1) ? i1 : i2;
        float4 xm = *(const float4*)(px + ib);   // global_load_dwordx4
        float4 ym = *(const float4*)(py + ib);
        float xl = px[ib + dl], xr = px[ib + dr];
        float yl = py[ib + dl], yr = py[ib + dr];
        if (eL) { xl = xm.y; yl = ym.y; }        // reflect(-1)=1
        if (eR) { xr = xm.z; yr = ym.z; }        // reflect(640)=638

        float x[6], y[6];
        x[0] = xl; x[1] = xm.x; x[2] = xm.y; x[3] = xm.z; x[4] = xm.w; x[5] = xr;
        y[0] = yl; y[1] = ym.x; y[2] = ym.y; y[3] = ym.z; y[4] = ym.w; y[5] = yr;

        float ss[6], pp[6];
#pragma unroll
        for (int i = 0; i < 6; i++) {
            ss[i] = fmaf(x[i], x[i], y[i] * y[i]);
            pp[i] = x[i] * y[i];
        }
#pragma unroll
        for (int i = 0; i < 4; i++) {
            ax[i]  += x[i]  + x[i + 1]  + x[i + 2];
            ay[i]  += y[i]  + y[i + 1]  + y[i + 2];
            as_[i] += ss[i] + ss[i + 1] + ss[i + 2];
            ap[i]  += pp[i] + pp[i + 1] + pp[i + 2];
        }
        if (rr == 1) {   // middle row = the output row
#pragma unroll
            for (int k = 0; k < 4; k++) dab[k] = fabsf(x[k + 1] - y[k + 1]);
        }
    }

    float p[4];
#pragma unroll
    for (int k = 0; k < 4; k++) {
        float mux = ax[k] * inv9;
        float muy = ay[k] * inv9;
        float mm  = mux * muy;
        float sigsum = fmaf(as_[k], inv9, -(mux + muy));   // faithful: -mu, not -mu^2
        float sigxy  = fmaf(ap[k], inv9, -mm);
        float num = fmaf(2.0f, mm, C1v) * fmaf(2.0f, sigxy, C2v);
        float den = fmaf(muy, muy, fmaf(mux, mux, C1v)) * (sigsum + C2v);
        float q   = num * __builtin_amdgcn_rcpf(den);
        float ns  = fmaf(q, -0.5f, 0.5f);
        ns = fminf(fmaxf(ns, 0.0f), 1.0f);
        p[k] = fmaf(wssim, ns, wl1 * dab[k]);
    }

    // ---- cross-channel reduction (one barrier) ----
    if (tz > 0) {
        *(float4*)&red[tz - 1][ty][tx][0] = make_float4(p[0], p[1], p[2], p[3]);
    }
    __syncthreads();
    if (tz == 0) {
        float4 q1 = *(const float4*)&red[0][ty][tx][0];
        float4 q2 = *(const float4*)&red[1][ty][tx][0];
        *(float4*)(out + ((size_t)b * HH + oh) * WW + c0) =
            make_float4(p[0] + q1.x + q2.x, p[1] + q1.y + q2.y,
                        p[2] + q1.z + q2.z, p[3] + q1.w + q2.w);
    }
}

extern "C" void kernel_launch(void* const* d_in, const int* in_sizes, int n_in,
                              void* d_out, int out_size, void* d_ws, size_t ws_size,
                              hipStream_t stream) {
    const float* src = (const float*)d_in[0];   // 'output'
    const float* tgt = (const float*)d_in[1];   // 'target'
    float* out = (float*)d_out;

    dim3 grid(NBX, NBY, BATCH);                 // (5, 96, 32) = 15360 blocks
    dim3 block(32, TR, CHAN);                   // 384 threads, channel-pure waves
    ssim_l1_kernel<<<grid, block, 0, stream>>>(src, tgt, out);
}